// Round 1
// baseline (2391.892 us; speedup 1.0000x reference)
//
#include <hip/hip_runtime.h>
#include <hip/hip_bf16.h>
#include <math.h>

// ---------------------------------------------------------------------------
// CategoricalDuelNetwork — live subgraph only (see dead-code analysis):
//   prep:   padded1 -> l2norm rows -> 11x11 cos-sim -> attended -> att1 (B,484)
//           m12 = max(pad(inputs), pad(input2))                      (B,484)
//   K2:     pooled = max(sigmoid(att1 @ W_g), m12)        GEMM K=484 N=484
//   K3:     p = pooled @ Wp^T + bp                        GEMM K=484 N=484
//   rnorm:  rn[b] = 1/max(||p_b||,1e-12)
//   K4:     x = [ rn*(p@Wffl^T)+bffl | p@Wao^T+bao ]      GEMM K=484 N=544
//   K5:     h = relu(x @ [Wa1;Wv1]^T + [ba1;bv1])         GEMM K=544 N=968
//   K6a:    adv = h_a @ Wa2^T + ba2  -> d_out             GEMM K=484 N=1530
//   K6b:    vf  = h_v @ Wv2^T + bv2                       GEMM K=484 N=51
//   soft:   q = vf + adv - mean_n(adv); softmax over 51 atoms -> d_out
// ---------------------------------------------------------------------------

#define NPART 11
#define MAXS  44
#define DDIM  484

__constant__ int c_sizes[NPART] = {11,29,29,29,11,29,29,1,44,30,30};
__constant__ int c_offs[NPART]  = {0,11,40,69,98,109,138,167,168,212,242};

// ---------------- prep: one wave per batch row ----------------
__global__ __launch_bounds__(64)
void k_prep(const float* __restrict__ in1, const float* __restrict__ in2,
            const float* __restrict__ ins,
            float* __restrict__ att1, float* __restrict__ m12)
{
    const int row  = blockIdx.x;
    const int lane = threadIdx.x;
    __shared__ float pad1[DDIM];
    __shared__ float invn[NPART];
    __shared__ float attnm[NPART*NPART];

    const float* x1 = in1 + (size_t)row * 272;
    for (int j = lane; j < DDIM; j += 64) {
        const int part = j / MAXS, c = j % MAXS;
        pad1[j] = (c < c_sizes[part]) ? x1[c_offs[part] + c] : 0.f;
    }
    __syncthreads();
    if (lane < NPART) {
        float ss = 0.f;
        const float* pr = &pad1[lane * MAXS];
        for (int k = 0; k < MAXS; ++k) ss += pr[k] * pr[k];
        invn[lane] = 1.f / fmaxf(sqrtf(ss), 1e-12f);
    }
    __syncthreads();
    for (int idx = lane; idx < NPART*NPART; idx += 64) {
        const int i = idx / NPART, j = idx % NPART;
        const float* pi = &pad1[i * MAXS];
        const float* pj = &pad1[j * MAXS];
        float d = 0.f;
        for (int k = 0; k < MAXS; ++k) d += pi[k] * pj[k];
        attnm[idx] = d * invn[i] * invn[j];
    }
    __syncthreads();
    const size_t ro = (size_t)row * DDIM;
    for (int j = lane; j < DDIM; j += 64) {
        const int i = j / MAXS, k = j % MAXS;
        float v = 0.f;
        #pragma unroll
        for (int t = 0; t < NPART; ++t) v += attnm[i*NPART + t] * pad1[t*MAXS + k];
        att1[ro + j] = v;
    }
    // m12 = max(pad(inputs), pad(input2))
    const float* x2 = in2 + (size_t)row * 272;
    const float* xs = ins + (size_t)row * 272;
    for (int j = lane; j < DDIM; j += 64) {
        const int part = j / MAXS, c = j % MAXS;
        float a = 0.f, b = 0.f;
        if (c < c_sizes[part]) { a = xs[c_offs[part] + c]; b = x2[c_offs[part] + c]; }
        m12[ro + j] = fmaxf(a, b);
    }
}

// ---------------- row 1/||p|| ----------------
__global__ __launch_bounds__(256)
void k_rnorm(const float* __restrict__ p, float* __restrict__ rnorm)
{
    const int row  = blockIdx.x * 4 + (threadIdx.x >> 6);
    const int lane = threadIdx.x & 63;
    const float* pr = p + (size_t)row * DDIM;
    float ss = 0.f;
    for (int j = lane; j < DDIM; j += 64) { const float v = pr[j]; ss += v * v; }
    #pragma unroll
    for (int o = 32; o; o >>= 1) ss += __shfl_xor(ss, o);
    if (lane == 0) rnorm[row] = 1.f / fmaxf(sqrtf(ss), 1e-12f);
}

// ---------------- tiled f32 GEMM: C = A @ W^T (+epilogue) ----------------
// A: (M,K) row-major, lda. Weight: WKN=false -> W (N,K) row-major (rows n>=nsplit
// come from W2); WKN=true -> W1 is (K,N) row-major (i.e. C = A @ W1).
// MODE 0: C = acc + bias            MODE 1: C = max(sigmoid(acc), C)   (in place)
// MODE 2: n<nsplit: extra[m]*acc+b1[n] else acc+b2[n-nsplit]
// MODE 3: C = relu(acc + bias)
template<int MODE, bool WKN>
__global__ __launch_bounds__(256)
void k_gemm(const float* __restrict__ A, int lda,
            const float* __restrict__ W1, const float* __restrict__ W2,
            int ldw, int nsplit,
            const float* __restrict__ b1, const float* __restrict__ b2,
            float* __restrict__ C, int ldc,
            const float* __restrict__ extra, int N, int K)
{
    __shared__ float As[8][132];
    __shared__ float Ws[8][132];
    const int tid = threadIdx.x;
    const int m0 = blockIdx.x * 128;
    const int n0 = blockIdx.y * 128;
    const int tm = tid >> 4;
    const int tn = tid & 15;
    float acc[2][2][4][4];
    #pragma unroll
    for (int a = 0; a < 2; ++a)
        #pragma unroll
        for (int b = 0; b < 2; ++b)
            #pragma unroll
            for (int i = 0; i < 4; ++i)
                #pragma unroll
                for (int j = 0; j < 4; ++j) acc[a][b][i][j] = 0.f;

    const int arow = tid >> 1;
    const int akv  = (tid & 1) * 4;
    const int nkt  = (K + 7) >> 3;
    for (int kt = 0; kt < nkt; ++kt) {
        const int k0 = kt * 8;
        {   // A tile 128x8 -> As[k][m]
            const float* ap = A + (size_t)(m0 + arow) * lda + k0 + akv;
            float4 v = make_float4(0.f, 0.f, 0.f, 0.f);
            if (k0 + akv + 3 < K) v = *(const float4*)ap;
            else {
                if (k0+akv+0 < K) v.x = ap[0];
                if (k0+akv+1 < K) v.y = ap[1];
                if (k0+akv+2 < K) v.z = ap[2];
            }
            As[akv+0][arow] = v.x; As[akv+1][arow] = v.y;
            As[akv+2][arow] = v.z; As[akv+3][arow] = v.w;
        }
        if (WKN) {  // W1 is (K,N): tile 8k x 128n, n-contiguous
            const int wk = tid >> 5;
            const int wn = (tid & 31) * 4;
            const int gn = n0 + wn;
            float4 v = make_float4(0.f, 0.f, 0.f, 0.f);
            if (k0 + wk < K) {
                const float* wp = W1 + (size_t)(k0 + wk) * ldw + gn;
                if (gn + 3 < N) v = *(const float4*)wp;
                else {
                    if (gn+0 < N) v.x = wp[0];
                    if (gn+1 < N) v.y = wp[1];
                    if (gn+2 < N) v.z = wp[2];
                }
            }
            *(float4*)&Ws[wk][wn] = v;
        } else {    // W (N,K): tile 128n x 8k -> Ws[k][n]
            const int wrow = tid >> 1;
            const int wkv  = (tid & 1) * 4;
            const int gn = n0 + wrow;
            float4 v = make_float4(0.f, 0.f, 0.f, 0.f);
            if (gn < N) {
                const float* wbase = (gn < nsplit) ? (W1 + (size_t)gn * ldw)
                                                   : (W2 + (size_t)(gn - nsplit) * ldw);
                const float* wp = wbase + k0 + wkv;
                if (k0 + wkv + 3 < K) v = *(const float4*)wp;
                else {
                    if (k0+wkv+0 < K) v.x = wp[0];
                    if (k0+wkv+1 < K) v.y = wp[1];
                    if (k0+wkv+2 < K) v.z = wp[2];
                }
            }
            Ws[wkv+0][wrow] = v.x; Ws[wkv+1][wrow] = v.y;
            Ws[wkv+2][wrow] = v.z; Ws[wkv+3][wrow] = v.w;
        }
        __syncthreads();
        #pragma unroll
        for (int kk = 0; kk < 8; ++kk) {
            const float4 a0 = *(const float4*)&As[kk][tm*4];
            const float4 a1 = *(const float4*)&As[kk][tm*4 + 64];
            const float4 w0 = *(const float4*)&Ws[kk][tn*4];
            const float4 w1 = *(const float4*)&Ws[kk][tn*4 + 64];
            const float av[2][4] = {{a0.x,a0.y,a0.z,a0.w},{a1.x,a1.y,a1.z,a1.w}};
            const float wv[2][4] = {{w0.x,w0.y,w0.z,w0.w},{w1.x,w1.y,w1.z,w1.w}};
            #pragma unroll
            for (int qi = 0; qi < 2; ++qi)
                #pragma unroll
                for (int i = 0; i < 4; ++i)
                    #pragma unroll
                    for (int qj = 0; qj < 2; ++qj)
                        #pragma unroll
                        for (int j = 0; j < 4; ++j)
                            acc[qi][qj][i][j] = fmaf(av[qi][i], wv[qj][j], acc[qi][qj][i][j]);
        }
        __syncthreads();
    }
    #pragma unroll
    for (int qi = 0; qi < 2; ++qi) {
        #pragma unroll
        for (int i = 0; i < 4; ++i) {
            const int m = m0 + qi*64 + tm*4 + i;
            float* crow = C + (size_t)m * ldc;
            #pragma unroll
            for (int qj = 0; qj < 2; ++qj) {
                #pragma unroll
                for (int j = 0; j < 4; ++j) {
                    const int n = n0 + qj*64 + tn*4 + j;
                    if (n >= N) continue;
                    const float v = acc[qi][qj][i][j];
                    float outv;
                    if (MODE == 0) {
                        outv = v + ((n < nsplit) ? b1[n] : b2[n - nsplit]);
                    } else if (MODE == 1) {
                        const float sg = 1.f / (1.f + expf(-v));
                        outv = fmaxf(sg, crow[n]);
                    } else if (MODE == 2) {
                        outv = (n < nsplit) ? (extra[m] * v + b1[n])
                                            : (v + b2[n - nsplit]);
                    } else {
                        outv = fmaxf(v + ((n < nsplit) ? b1[n] : b2[n - nsplit]), 0.f);
                    }
                    crow[n] = outv;
                }
            }
        }
    }
}

// ---------------- dueling combine + softmax(51) ----------------
__global__ __launch_bounds__(256)
void k_soft(float* __restrict__ out, const float* __restrict__ vf)
{
    const int row = blockIdx.x;
    const int tid = threadIdx.x;
    __shared__ float s_adv[30*51];
    __shared__ float s_vfm[51];
    float* orow = out + (size_t)row * (30*51);
    for (int j = tid; j < 30*51; j += 256) s_adv[j] = orow[j];
    __syncthreads();
    if (tid < 51) {
        float s = 0.f;
        #pragma unroll
        for (int n = 0; n < 30; ++n) s += s_adv[n*51 + tid];
        s_vfm[tid] = vf[(size_t)row*51 + tid] - s * (1.f/30.f);
    }
    __syncthreads();
    const int w = tid >> 6, lane = tid & 63;
    for (int n = w; n < 30; n += 4) {
        const float v = (lane < 51) ? (s_adv[n*51 + lane] + s_vfm[lane]) : -INFINITY;
        float mx = v;
        #pragma unroll
        for (int o = 32; o; o >>= 1) mx = fmaxf(mx, __shfl_xor(mx, o));
        const float e = (lane < 51) ? expf(v - mx) : 0.f;
        float s = e;
        #pragma unroll
        for (int o = 32; o; o >>= 1) s += __shfl_xor(s, o);
        if (lane < 51) orow[n*51 + lane] = e / s;
    }
}

// ---------------------------------------------------------------------------
extern "C" void kernel_launch(void* const* d_in, const int* in_sizes, int n_in,
                              void* d_out, int out_size, void* d_ws, size_t ws_size,
                              hipStream_t stream)
{
    const float* in1  = (const float*)d_in[0];
    const float* in2  = (const float*)d_in[1];
    const float* ins  = (const float*)d_in[2];
    const float* W_g  = (const float*)d_in[3];
    // d_in[4]=Wff, d_in[5]=bff : dead
    const float* Wffl = (const float*)d_in[6];
    const float* bffl = (const float*)d_in[7];
    // d_in[8..11] = Wp1,bp1,Wp2,bp2 : dead
    const float* Wp   = (const float*)d_in[12];
    const float* bp   = (const float*)d_in[13];
    const float* Wao  = (const float*)d_in[14];
    const float* bao  = (const float*)d_in[15];
    const float* Wa1  = (const float*)d_in[16];
    const float* ba1  = (const float*)d_in[17];
    const float* Wa2  = (const float*)d_in[18];
    const float* ba2  = (const float*)d_in[19];
    const float* Wv1  = (const float*)d_in[20];
    const float* bv1  = (const float*)d_in[21];
    const float* Wv2  = (const float*)d_in[22];
    const float* bv2  = (const float*)d_in[23];

    const int B = in_sizes[0] / 272;   // 32768

    // ws layout (floats):  [att1 | m12] (each B*484; later reused: p over att1,
    // h over both halves contiguously) ; vf (B*51) ; rnorm (B).
    // x (B*544) lives in d_out until K5 consumes it.  ws need = B*1020*4 ≈ 134 MB.
    float* ws    = (float*)d_ws;
    float* att1  = ws;
    float* m12   = ws + (size_t)B * DDIM;        // pooled in-place
    float* vf    = ws + (size_t)B * (2*DDIM);
    float* rnorm = ws + (size_t)B * (2*DDIM + 51);
    float* p     = att1;                         // after att1 is dead
    float* h     = att1;                         // B x 968 over [att1|m12]
    float* xbuf  = (float*)d_out;                // B x 544 scratch, then adv/out
    float* out   = (float*)d_out;

    const dim3 blk(256);
    const int  gm = B / 128;

    k_prep<<<B, 64, 0, stream>>>(in1, in2, ins, att1, m12);
    // pooled = max(sigmoid(att1 @ W_g), m12)   (W_g is K x N -> WKN)
    k_gemm<1, true ><<<dim3(gm,  4), blk, 0, stream>>>(att1, DDIM, W_g, nullptr, DDIM, DDIM,
                                                       nullptr, nullptr, m12, DDIM, nullptr, DDIM, DDIM);
    // p = pooled @ Wp^T + bp
    k_gemm<0, false><<<dim3(gm,  4), blk, 0, stream>>>(m12, DDIM, Wp, nullptr, DDIM, DDIM,
                                                       bp, nullptr, p, DDIM, nullptr, DDIM, DDIM);
    k_rnorm<<<B / 4, 256, 0, stream>>>(p, rnorm);
    // x = [ rnorm*(p@Wffl^T)+bffl | p@Wao^T+bao ]
    k_gemm<2, false><<<dim3(gm,  5), blk, 0, stream>>>(p, DDIM, Wffl, Wao, DDIM, 272,
                                                       bffl, bao, xbuf, 544, rnorm, 544, DDIM);
    // h = relu(x @ [Wa1;Wv1]^T + [ba1;bv1])
    k_gemm<3, false><<<dim3(gm,  8), blk, 0, stream>>>(xbuf, 544, Wa1, Wv1, 544, DDIM,
                                                       ba1, bv1, h, 968, nullptr, 968, 544);
    // adv = h_a @ Wa2^T + ba2  -> d_out
    k_gemm<0, false><<<dim3(gm, 12), blk, 0, stream>>>(h, 968, Wa2, nullptr, DDIM, 1530,
                                                       ba2, nullptr, out, 1530, nullptr, 1530, DDIM);
    // vf = h_v @ Wv2^T + bv2
    k_gemm<0, false><<<dim3(gm,  1), blk, 0, stream>>>(h + DDIM, 968, Wv2, nullptr, DDIM, 51,
                                                       bv2, nullptr, vf, 51, nullptr, 51, DDIM);
    k_soft<<<B, 256, 0, stream>>>(out, vf);
}

// Round 10
// 1821.480 us; speedup vs baseline: 1.3132x; 1.3132x over previous
//
#include <hip/hip_runtime.h>
#include <hip/hip_bf16.h>
#include <math.h>

// ---------------------------------------------------------------------------
// Round 9 (resubmit, k_prep staging bug fixed): MFMA pipeline (527us measured)
// + three fixes:
//  - adv stored bf16 in d_out (row stride 6120B = output row), vf fused into
//    k_soft (4 rows/block) -> kills 50us vf GEMM + 300MB traffic
//  - k_prep reads only input1 (m12 folded into K2 epilogue via direct gathers)
//  - GEMM grid n-major (blockIdx.x = n) so A-panel is fetched once
// Live graph: prep -> K2(pooled=max(sigmoid(att1@Wg), max(pad_ins,pad_in2)))
//  -> K3(p) -> rnorm -> K4(x) -> K5(h) -> K6a(adv bf16) -> soft(vf+duel+softmax)
// ---------------------------------------------------------------------------

#define NPART 11
#define MAXS  44

typedef __attribute__((ext_vector_type(8))) short bfrag8;
typedef __attribute__((ext_vector_type(4))) float f32x4;

__constant__ int c_sizes[NPART] = {11,29,29,29,11,29,29,1,44,30,30};
__constant__ int c_offs[NPART]  = {0,11,40,69,98,109,138,167,168,212,242};

__device__ __forceinline__ unsigned short f2bf(float f) {
    unsigned int u = __builtin_bit_cast(unsigned int, f);
    u += 0x7fffu + ((u >> 16) & 1u);
    return (unsigned short)(u >> 16);
}
__device__ __forceinline__ float bf2f(unsigned short h) {
    unsigned int u = ((unsigned int)h) << 16;
    return __builtin_bit_cast(float, u);
}
// magic divides (verified at range boundaries): n/44 for n<512 ; i/11 for i<121
__device__ __forceinline__ int div44(int n) { return (n * 373) >> 14; }
__device__ __forceinline__ int div11(int n) { return (n * 745) >> 13; }

// ---------------- weight conversion / padding (per call) --------------------
__global__ __launch_bounds__(256)
void k_conv(const float* __restrict__ Wg,  const float* __restrict__ Wp,
            const float* __restrict__ Wffl,const float* __restrict__ Wao,
            const float* __restrict__ Wa1, const float* __restrict__ Wv1,
            const float* __restrict__ Wa2, const float* __restrict__ Wv2,
            const float* __restrict__ bp,  const float* __restrict__ bffl,
            const float* __restrict__ bao, const float* __restrict__ ba1,
            const float* __restrict__ bv1, const float* __restrict__ ba2,
            const float* __restrict__ bv2,
            unsigned short* __restrict__ wgT, unsigned short* __restrict__ wp,
            unsigned short* __restrict__ w4,  unsigned short* __restrict__ w5,
            unsigned short* __restrict__ wa2, unsigned short* __restrict__ wv2,
            float* __restrict__ biases)
{
    const int seg = blockIdx.y;
    const int i = blockIdx.x * 256 + threadIdx.x;
    if (seg == 0) {            // wgT (512,512) = Wg^T
        if (i < 512*512) { int n = i >> 9, k = i & 511;
            wgT[i] = (n < 484 && k < 484) ? f2bf(Wg[k*484 + n]) : 0; }
    } else if (seg == 1) {     // wp (512,512)
        if (i < 512*512) { int n = i >> 9, k = i & 511;
            wp[i] = (n < 484 && k < 484) ? f2bf(Wp[n*484 + k]) : 0; }
    } else if (seg == 2) {     // w4 (640,512) = [Wffl;Wao;0]
        if (i < 640*512) { int n = i >> 9, k = i & 511;
            float v = 0.f;
            if (k < 484) { if (n < 272) v = Wffl[n*484+k];
                           else if (n < 544) v = Wao[(n-272)*484+k]; }
            w4[i] = f2bf(v); }
    } else if (seg == 3) {     // w5 (1024,576): rows 0-483 Wa1, 512-995 Wv1
        if (i < 1024*576) { int n = i / 576, k = i % 576;
            float v = 0.f;
            if (k < 544) { if (n < 484) v = Wa1[n*544+k];
                           else if (n >= 512 && n < 996) v = Wv1[(n-512)*544+k]; }
            w5[i] = f2bf(v); }
    } else if (seg == 4) {     // wa2 (1536,512)
        if (i < 1536*512) { int n = i >> 9, k = i & 511;
            wa2[i] = (n < 1530 && k < 484) ? f2bf(Wa2[n*484+k]) : 0; }
    } else if (seg == 5) {     // wv2 (128,512)
        if (i < 128*512) { int n = i >> 9, k = i & 511;
            wv2[i] = (n < 51 && k < 484) ? f2bf(Wv2[n*484+k]) : 0; }
    } else {                   // biases: bp(512) b4(640) b5(1024) ba2(1536) bv2(128)
        if (i < 3840) {
            float v = 0.f;
            if (i < 512)       { if (i < 484) v = bp[i]; }
            else if (i < 1152) { int j = i-512;  v = (j<272)? bffl[j] : (j<544? bao[j-272] : 0.f); }
            else if (i < 2176) { int j = i-1152; v = (j<484)? ba1[j] : ((j>=512&&j<996)? bv1[j-512] : 0.f); }
            else if (i < 3712) { int j = i-2176; if (j < 1530) v = ba2[j]; }
            else               { int j = i-3712; if (j < 51)   v = bv2[j]; }
            biases[i] = v;
        }
    }
}

// ---------------- prep: input1 only -> att1 bf16 (B,512) ----------------
__global__ __launch_bounds__(64)
void k_prep(const float* __restrict__ in1, unsigned short* __restrict__ att1)
{
    const int row  = blockIdx.x;
    const int lane = threadIdx.x;
    __shared__ float x1s[272];
    __shared__ float pad1[484];
    __shared__ float invn[NPART];
    __shared__ float attnm[NPART*NPART];

    for (int i = lane; i < 68; i += 64)   // 68 float4 chunks, 64 lanes
        *(float4*)&x1s[i*4] = ((const float4*)(in1 + (size_t)row * 272))[i];
    __syncthreads();
    for (int j = lane; j < 484; j += 64) {
        const int part = div44(j), c = j - part*44;
        pad1[j] = (c < c_sizes[part]) ? x1s[c_offs[part] + c] : 0.f;
    }
    __syncthreads();
    {   // 44 lanes: part=lane>>2, quarter q sums 11 elems; combine over 4 lanes
        float ps = 0.f;
        if (lane < 44) {
            const int part = lane >> 2, q = lane & 3;
            const float* pr = &pad1[part*44 + q*11];
            #pragma unroll
            for (int k = 0; k < 11; ++k) ps += pr[k]*pr[k];
        }
        ps += __shfl_xor(ps, 1); ps += __shfl_xor(ps, 2);
        if (lane < 44 && (lane & 3) == 0)
            invn[lane >> 2] = 1.f / fmaxf(sqrtf(ps), 1e-12f);
    }
    __syncthreads();
    for (int idx = lane; idx < 121; idx += 64) {
        const int i = div11(idx), j = idx - i*11;
        const float* pi = &pad1[i * 44];
        const float* pj = &pad1[j * 44];
        float d = 0.f;
        #pragma unroll 4
        for (int k = 0; k < 44; ++k) d += pi[k] * pj[k];
        attnm[idx] = d * invn[i] * invn[j];
    }
    __syncthreads();
    const size_t ro = (size_t)row * 512;
    for (int j = lane; j < 512; j += 64) {
        float v = 0.f;
        if (j < 484) {
            const int i = div44(j), k = j - i*44;
            #pragma unroll
            for (int t = 0; t < NPART; ++t) v += attnm[i*NPART + t] * pad1[t*44 + k];
        }
        att1[ro + j] = f2bf(v);
    }
}

// ---------------- rnorm over bf16 p (stride 512, cols>=484 zero) ------------
__global__ __launch_bounds__(256)
void k_rnorm(const unsigned short* __restrict__ p, float* __restrict__ rnorm)
{
    const int row  = blockIdx.x * 4 + (threadIdx.x >> 6);
    const int lane = threadIdx.x & 63;
    const bfrag8 v8 = *(const bfrag8*)(p + (size_t)row * 512 + lane * 8);
    float ss = 0.f;
    #pragma unroll
    for (int t = 0; t < 8; ++t) { const float f = bf2f((unsigned short)v8[t]); ss += f*f; }
    #pragma unroll
    for (int o = 32; o; o >>= 1) ss += __shfl_xor(ss, o);
    if (lane == 0) rnorm[row] = 1.f / fmaxf(sqrtf(ss), 1e-12f);
}

// ---------------- bf16 MFMA GEMM: C = A(M,K) @ W(N,K)^T + epilogue ----------
// MODE 0: acc + bias[n]
// MODE 1: n<484 ? max(sigmoid(acc), max(ins_pad, in2_pad)) : 0
//         (extra=ins, m12=in2 ; gathers via magic-div pad mapping)
// MODE 2: (n<272 ? rn[m]*acc : acc) + bias[n]   (extra=rnorm)
// MODE 3: relu(acc + bias[n])
// Grid is (n-blocks, m-blocks): consecutive blocks share the A row-panel.
template<int MODE, typename CT>
__global__ __launch_bounds__(256)
void k_gemm_mfma(const unsigned short* __restrict__ A, int lda,
                 const unsigned short* __restrict__ W, int ldw,
                 CT* __restrict__ C, int ldc,
                 const float* __restrict__ bias,
                 const float* __restrict__ extra,
                 const float* __restrict__ m12,
                 int K, int NSTORE)
{
    __shared__ unsigned short Asm[128*64];
    __shared__ unsigned short Bsm[128*64];
    const int tid  = threadIdx.x;
    const int wave = tid >> 6, lane = tid & 63;
    const int m0 = blockIdx.y * 128;
    const int n0 = blockIdx.x * 128;
    const int wr = (wave >> 1) << 6;
    const int wc = (wave & 1) << 6;

    f32x4 acc[4][4];
    #pragma unroll
    for (int i = 0; i < 4; ++i)
        #pragma unroll
        for (int j = 0; j < 4; ++j) acc[i][j] = (f32x4){0.f,0.f,0.f,0.f};

    const int ci_base = wave * 64 + lane;
    const int lrow = lane & 15;
    const int lk   = lane >> 4;

    const int nkt = K >> 6;
    for (int kt = 0; kt < nkt; ++kt) {
        const int k0 = kt << 6;
        #pragma unroll
        for (int c = 0; c < 4; ++c) {
            const int ci   = c * 256 + ci_base;
            const int row  = ci >> 3;
            const int slot = ci & 7;
            const int gc   = k0 + (((slot ^ (row & 7)) & 7) << 3);
            __builtin_amdgcn_global_load_lds(
                (const __attribute__((address_space(1))) void*)(A + (size_t)(m0 + row) * lda + gc),
                (__attribute__((address_space(3))) void*)(Asm + (c*4 + wave) * 512),
                16, 0, 0);
            __builtin_amdgcn_global_load_lds(
                (const __attribute__((address_space(1))) void*)(W + (size_t)(n0 + row) * ldw + gc),
                (__attribute__((address_space(3))) void*)(Bsm + (c*4 + wave) * 512),
                16, 0, 0);
        }
        __syncthreads();
        #pragma unroll
        for (int kk = 0; kk < 2; ++kk) {
            bfrag8 af[4], bfr[4];
            #pragma unroll
            for (int f = 0; f < 4; ++f) {
                const int r = wr + f*16 + lrow;
                const int s = kk*4 + lk;
                af[f]  = *(const bfrag8*)((const char*)Asm + r*128 + ((s ^ (r & 7)) << 4));
                const int n = wc + f*16 + lrow;
                bfr[f] = *(const bfrag8*)((const char*)Bsm + n*128 + ((s ^ (n & 7)) << 4));
            }
            #pragma unroll
            for (int i = 0; i < 4; ++i)
                #pragma unroll
                for (int j = 0; j < 4; ++j)
                    acc[i][j] = __builtin_amdgcn_mfma_f32_16x16x32_bf16(af[i], bfr[j], acc[i][j], 0, 0, 0);
        }
        __syncthreads();
    }

    const int lr4 = (lane >> 4) << 2;
    const int lc  = lane & 15;
    #pragma unroll
    for (int i = 0; i < 4; ++i) {
        #pragma unroll
        for (int r = 0; r < 4; ++r) {
            const int m = m0 + wr + i*16 + lr4 + r;
            CT* crow = C + (size_t)m * ldc;
            float ex = 0.f;
            if (MODE == 2) ex = extra[m];
            #pragma unroll
            for (int j = 0; j < 4; ++j) {
                const int n = n0 + wc + j*16 + lc;
                if (n >= NSTORE) continue;
                const float a = acc[i][j][r];
                float v;
                if (MODE == 0)      v = a + bias[n];
                else if (MODE == 1) {
                    if (n < 484) {
                        const int part = div44(n), c2 = n - part*44;
                        float mv = 0.f;
                        if (c2 < c_sizes[part]) {
                            const int so = c_offs[part] + c2;
                            mv = fmaxf(extra[(size_t)m*272 + so], m12[(size_t)m*272 + so]);
                        }
                        v = fmaxf(1.f/(1.f + expf(-a)), mv);
                    } else v = 0.f;
                }
                else if (MODE == 2) v = ((n < 272) ? ex * a : a) + bias[n];
                else                v = fmaxf(a + bias[n], 0.f);
                if constexpr (sizeof(CT) == 2) crow[n] = (CT)f2bf(v);
                else                           crow[n] = v;
            }
        }
    }
}

// ---------------- fused vf + dueling combine + softmax(51), 4 rows/block ----
// adv is bf16 in d_out, row stride 6120 bytes (= one f32 output row), so each
// block's read region is exactly its own write region (LDS-staged, race-free).
__global__ __launch_bounds__(256)
void k_soft(float* out, const unsigned short* __restrict__ h,
            const unsigned short* __restrict__ wv2, const float* __restrict__ bv2)
{
    const int base = blockIdx.x * 4;
    const int tid  = threadIdx.x;
    __shared__ float s_adv[4][1530];
    __shared__ float s_hv[4][512];
    __shared__ float s_q[4][51];

    #pragma unroll
    for (int r = 0; r < 4; ++r) {
        const unsigned int* arow = (const unsigned int*)(out + (size_t)(base + r) * 1530);
        for (int i = tid; i < 765; i += 256) {
            const unsigned int u = arow[i];
            s_adv[r][2*i]   = bf2f((unsigned short)(u & 0xffffu));
            s_adv[r][2*i+1] = bf2f((unsigned short)(u >> 16));
        }
    }
    {   // h_v rows: thread t -> row t>>6, 16B chunk lane
        const int r = tid >> 6, lane = tid & 63;
        const bfrag8 hv = *(const bfrag8*)(h + (size_t)(base + r) * 1024 + 512 + lane * 8);
        #pragma unroll
        for (int t = 0; t < 8; ++t) s_hv[r][lane*8 + t] = bf2f((unsigned short)hv[t]);
    }
    __syncthreads();

    if (tid < 204) {
        const int a = tid >> 2, q = tid & 3;
        float vfp[4] = {0.f,0.f,0.f,0.f};
        const unsigned short* wp = wv2 + a*512 + q*128;
        for (int ch = 0; ch < 16; ++ch) {
            const bfrag8 w8 = *(const bfrag8*)(wp + ch*8);
            #pragma unroll
            for (int t = 0; t < 8; ++t) {
                const float wv = bf2f((unsigned short)w8[t]);
                const int k = q*128 + ch*8 + t;
                #pragma unroll
                for (int r = 0; r < 4; ++r) vfp[r] = fmaf(s_hv[r][k], wv, vfp[r]);
            }
        }
        float csp[4] = {0.f,0.f,0.f,0.f};
        const int cnt = (q < 3) ? 8 : 6;
        for (int u = 0; u < cnt; ++u) {
            const int n = q*8 + u;
            #pragma unroll
            for (int r = 0; r < 4; ++r) csp[r] += s_adv[r][n*51 + a];
        }
        #pragma unroll
        for (int r = 0; r < 4; ++r) {
            vfp[r] += __shfl_xor(vfp[r], 1); vfp[r] += __shfl_xor(vfp[r], 2);
            csp[r] += __shfl_xor(csp[r], 1); csp[r] += __shfl_xor(csp[r], 2);
        }
        if (q == 0) {
            const float b = bv2[a];
            #pragma unroll
            for (int r = 0; r < 4; ++r) s_q[r][a] = vfp[r] + b - csp[r] * (1.f/30.f);
        }
    }
    __syncthreads();

    const int w = tid >> 6, lane = tid & 63;
    #pragma unroll
    for (int r = 0; r < 4; ++r) {
        float* orow = out + (size_t)(base + r) * 1530;
        for (int n = w; n < 30; n += 4) {
            const float v = (lane < 51) ? (s_adv[r][n*51 + lane] + s_q[r][lane]) : -INFINITY;
            float mx = v;
            #pragma unroll
            for (int o = 32; o; o >>= 1) mx = fmaxf(mx, __shfl_xor(mx, o));
            const float e = (lane < 51) ? expf(v - mx) : 0.f;
            float s = e;
            #pragma unroll
            for (int o = 32; o; o >>= 1) s += __shfl_xor(s, o);
            if (lane < 51) orow[n*51 + lane] = e / s;
        }
    }
}

// ---------------------------------------------------------------------------
extern "C" void kernel_launch(void* const* d_in, const int* in_sizes, int n_in,
                              void* d_out, int out_size, void* d_ws, size_t ws_size,
                              hipStream_t stream)
{
    const float* in1  = (const float*)d_in[0];
    const float* in2  = (const float*)d_in[1];
    const float* ins  = (const float*)d_in[2];
    const float* W_g  = (const float*)d_in[3];
    const float* Wffl = (const float*)d_in[6];
    const float* bffl = (const float*)d_in[7];
    const float* Wp   = (const float*)d_in[12];
    const float* bp   = (const float*)d_in[13];
    const float* Wao  = (const float*)d_in[14];
    const float* bao  = (const float*)d_in[15];
    const float* Wa1  = (const float*)d_in[16];
    const float* ba1  = (const float*)d_in[17];
    const float* Wa2  = (const float*)d_in[18];
    const float* ba2  = (const float*)d_in[19];
    const float* Wv1  = (const float*)d_in[20];
    const float* bv1  = (const float*)d_in[21];
    const float* Wv2  = (const float*)d_in[22];
    const float* bv2  = (const float*)d_in[23];

    const int B = in_sizes[0] / 272;   // 32768

    // ws layout (bytes): [0,B*2048) h (B,1024bf16); early att1@0, pooled@B*1024
    //   [B*2048,B*3072) p (B,512bf16) ; [B*3072,+B*204) spare ; rnorm ; weights
    char* ws = (char*)d_ws;
    unsigned short* att1   = (unsigned short*)ws;
    unsigned short* pooled = (unsigned short*)(ws + (size_t)B * 1024);
    unsigned short* hbuf   = (unsigned short*)ws;
    unsigned short* pbuf   = (unsigned short*)(ws + (size_t)B * 2048);
    float*          rnorm  = (float*)(ws + (size_t)B * 3072 + (size_t)B * 204);
    unsigned short* wgT    = (unsigned short*)((char*)rnorm + (size_t)B * 4);
    unsigned short* wpw    = wgT + 512*512;
    unsigned short* w4     = wpw + 512*512;
    unsigned short* w5     = w4  + 640*512;
    unsigned short* wa2    = w5  + 1024*576;
    unsigned short* wv2    = wa2 + 1536*512;
    float*          biases = (float*)(wv2 + 128*512);

    // d_out: x_bf (B,576) scratch at float offset B*512 until K5; then adv bf16
    // with row stride 3060 ushorts (=6120B = one f32 out row); then final f32.
    unsigned short* xbuf = (unsigned short*)((float*)d_out + (size_t)B * 512);
    unsigned short* advb = (unsigned short*)d_out;
    float*          out  = (float*)d_out;

    const int gm = B / 128;

    k_conv<<<dim3(3072, 7), 256, 0, stream>>>(W_g, Wp, Wffl, Wao, Wa1, Wv1, Wa2, Wv2,
                                              bp, bffl, bao, ba1, bv1, ba2, bv2,
                                              wgT, wpw, w4, w5, wa2, wv2, biases);
    k_prep<<<B, 64, 0, stream>>>(in1, att1);
    // pooled = max(sigmoid(att1 @ W_g), max(pad(ins), pad(in2)))
    k_gemm_mfma<1, unsigned short><<<dim3(4, gm), 256, 0, stream>>>(
        att1, 512, wgT, 512, pooled, 512, nullptr, ins, in2, 512, 512);
    // p = pooled @ Wp^T + bp
    k_gemm_mfma<0, unsigned short><<<dim3(4, gm), 256, 0, stream>>>(
        pooled, 512, wpw, 512, pbuf, 512, biases + 0, nullptr, nullptr, 512, 512);
    k_rnorm<<<B / 4, 256, 0, stream>>>(pbuf, rnorm);
    // x = [rn*(p@Wffl^T)+bffl | p@Wao^T+bao]  (B,576)
    k_gemm_mfma<2, unsigned short><<<dim3(5, gm), 256, 0, stream>>>(
        pbuf, 512, w4, 512, xbuf, 576, biases + 512, rnorm, nullptr, 512, 576);
    // h = relu(x @ w5^T + b5)  (B,1024)
    k_gemm_mfma<3, unsigned short><<<dim3(8, gm), 256, 0, stream>>>(
        xbuf, 576, w5, 576, hbuf, 1024, biases + 1152, nullptr, nullptr, 576, 1024);
    // adv = h[:, :512] @ Wa2^T + ba2 -> bf16 in d_out, row stride 3060 ushorts
    k_gemm_mfma<0, unsigned short><<<dim3(12, gm), 256, 0, stream>>>(
        hbuf, 1024, wa2, 512, advb, 3060, biases + 2176, nullptr, nullptr, 512, 1536);
    // fused vf + dueling + softmax
    k_soft<<<B / 4, 256, 0, stream>>>(out, hbuf, wv2, biases + 3712);
}

// Round 11
// 948.064 us; speedup vs baseline: 2.5229x; 1.9213x over previous
//
#include <hip/hip_runtime.h>
#include <hip/hip_bf16.h>
#include <math.h>

// ---------------------------------------------------------------------------
// Round 10 = round-8 base (527us measured) + surgical subset:
//  - combined adv+vf GEMM: K=1024, W=[[Wa2,0];[0,Wv2]] (N=1664, MODE 4):
//    adv -> bf16 in d_out (row stride 6120B = one f32 out row), vf -> f32 buf.
//    Kills the 50us MfmaUtil=0 vf dispatch.
//  - k_soft: round-8 structure verbatim (26 VGPR / 0 conflicts / 96% occ
//    measured), only reads adv as bf16 (stride-2 LDS unpack = 2-way free).
//  - k_prep: float4 staging + parallel norms + magic div, m12 kept here so
//    K2 stays byte-identical to round 8.
// REVERTED from round 9: 4-row fused k_soft (1100us: 256 VGPR, 44.6M bank
// conflicts), K2 gather epilogue, n-major grid.
// ---------------------------------------------------------------------------

#define NPART 11

typedef __attribute__((ext_vector_type(8))) short bfrag8;
typedef __attribute__((ext_vector_type(4))) float f32x4;

__constant__ int c_sizes[NPART] = {11,29,29,29,11,29,29,1,44,30,30};
__constant__ int c_offs[NPART]  = {0,11,40,69,98,109,138,167,168,212,242};

__device__ __forceinline__ unsigned short f2bf(float f) {
    unsigned int u = __builtin_bit_cast(unsigned int, f);
    u += 0x7fffu + ((u >> 16) & 1u);
    return (unsigned short)(u >> 16);
}
__device__ __forceinline__ float bf2f(unsigned short h) {
    unsigned int u = ((unsigned int)h) << 16;
    return __builtin_bit_cast(float, u);
}
// magic divides (verified at range boundaries): n/44 for n<512 ; i/11 for i<121
__device__ __forceinline__ int div44(int n) { return (n * 373) >> 14; }
__device__ __forceinline__ int div11(int n) { return (n * 745) >> 13; }

// ---------------- weight conversion / padding (per call) --------------------
__global__ __launch_bounds__(256)
void k_conv(const float* __restrict__ Wg,  const float* __restrict__ Wp,
            const float* __restrict__ Wffl,const float* __restrict__ Wao,
            const float* __restrict__ Wa1, const float* __restrict__ Wv1,
            const float* __restrict__ Wa2, const float* __restrict__ Wv2,
            const float* __restrict__ bp,  const float* __restrict__ bffl,
            const float* __restrict__ bao, const float* __restrict__ ba1,
            const float* __restrict__ bv1, const float* __restrict__ ba2,
            const float* __restrict__ bv2,
            unsigned short* __restrict__ wgT, unsigned short* __restrict__ wp,
            unsigned short* __restrict__ w4,  unsigned short* __restrict__ w5,
            unsigned short* __restrict__ wcomb,
            float* __restrict__ biases)
{
    const int seg = blockIdx.y;
    const int i = blockIdx.x * 256 + threadIdx.x;
    if (seg == 0) {            // wgT (512,512) = Wg^T
        if (i < 512*512) { int n = i >> 9, k = i & 511;
            wgT[i] = (n < 484 && k < 484) ? f2bf(Wg[k*484 + n]) : 0; }
    } else if (seg == 1) {     // wp (512,512)
        if (i < 512*512) { int n = i >> 9, k = i & 511;
            wp[i] = (n < 484 && k < 484) ? f2bf(Wp[n*484 + k]) : 0; }
    } else if (seg == 2) {     // w4 (640,512) = [Wffl;Wao;0]
        if (i < 640*512) { int n = i >> 9, k = i & 511;
            float v = 0.f;
            if (k < 484) { if (n < 272) v = Wffl[n*484+k];
                           else if (n < 544) v = Wao[(n-272)*484+k]; }
            w4[i] = f2bf(v); }
    } else if (seg == 3) {     // w5 (1024,576): rows 0-483 Wa1, 512-995 Wv1
        if (i < 1024*576) { int n = i / 576, k = i % 576;
            float v = 0.f;
            if (k < 544) { if (n < 484) v = Wa1[n*544+k];
                           else if (n >= 512 && n < 996) v = Wv1[(n-512)*544+k]; }
            w5[i] = f2bf(v); }
    } else if (seg == 4) {     // wcomb (1664,1024): [[Wa2,0];[0,Wv2]]
        #pragma unroll
        for (int e = 0; e < 4; ++e) {
            const int i4 = i * 4 + e;
            if (i4 < 1664*1024) {
                const int n = i4 >> 10, k = i4 & 1023;
                float v = 0.f;
                if (n < 1530 && k < 484) v = Wa2[n*484 + k];
                else if (n >= 1536 && n < 1587 && k >= 512 && k < 996)
                    v = Wv2[(n-1536)*484 + (k-512)];
                wcomb[i4] = f2bf(v);
            }
        }
    } else {                   // biases: bp(512) b4(640) b5(1024) bcomb(1664)
        if (i < 3840) {
            float v = 0.f;
            if (i < 512)       { if (i < 484) v = bp[i]; }
            else if (i < 1152) { int j = i-512;  v = (j<272)? bffl[j] : (j<544? bao[j-272] : 0.f); }
            else if (i < 2176) { int j = i-1152; v = (j<484)? ba1[j] : ((j>=512&&j<996)? bv1[j-512] : 0.f); }
            else               { int j = i-2176;
                                 if (j < 1530) v = ba2[j];
                                 else if (j >= 1536 && j < 1587) v = bv2[j-1536]; }
            biases[i] = v;
        }
    }
}

// ---------------- prep: att1 bf16 (B,512) + m12 f32 (B,484) ----------------
__global__ __launch_bounds__(64)
void k_prep(const float* __restrict__ in1, const float* __restrict__ in2,
            const float* __restrict__ ins,
            unsigned short* __restrict__ att1, float* __restrict__ m12)
{
    const int row  = blockIdx.x;
    const int lane = threadIdx.x;
    __shared__ float x1s[272], x2s[272], xss[272];
    __shared__ float pad1[484];
    __shared__ float invn[NPART];
    __shared__ float attnm[NPART*NPART];

    for (int i = lane; i < 68; i += 64) {
        *(float4*)&x1s[i*4] = ((const float4*)(in1 + (size_t)row * 272))[i];
        *(float4*)&x2s[i*4] = ((const float4*)(in2 + (size_t)row * 272))[i];
        *(float4*)&xss[i*4] = ((const float4*)(ins + (size_t)row * 272))[i];
    }
    __syncthreads();
    for (int j = lane; j < 484; j += 64) {
        const int part = div44(j), c = j - part*44;
        pad1[j] = (c < c_sizes[part]) ? x1s[c_offs[part] + c] : 0.f;
    }
    __syncthreads();
    {   // 44 lanes: part=lane>>2, quarter q sums 11 elems; combine over 4 lanes
        float ps = 0.f;
        if (lane < 44) {
            const int part = lane >> 2, q = lane & 3;
            const float* pr = &pad1[part*44 + q*11];
            #pragma unroll
            for (int k = 0; k < 11; ++k) ps += pr[k]*pr[k];
        }
        ps += __shfl_xor(ps, 1); ps += __shfl_xor(ps, 2);
        if (lane < 44 && (lane & 3) == 0)
            invn[lane >> 2] = 1.f / fmaxf(sqrtf(ps), 1e-12f);
    }
    __syncthreads();
    for (int idx = lane; idx < 121; idx += 64) {
        const int i = div11(idx), j = idx - i*11;
        const float* pi = &pad1[i * 44];
        const float* pj = &pad1[j * 44];
        float d = 0.f;
        #pragma unroll 4
        for (int k = 0; k < 44; ++k) d += pi[k] * pj[k];
        attnm[idx] = d * invn[i] * invn[j];
    }
    __syncthreads();
    const size_t ro = (size_t)row * 512;
    for (int j = lane; j < 512; j += 64) {
        float v = 0.f;
        if (j < 484) {
            const int i = div44(j), k = j - i*44;
            #pragma unroll
            for (int t = 0; t < NPART; ++t) v += attnm[i*NPART + t] * pad1[t*44 + k];
        }
        att1[ro + j] = f2bf(v);
    }
    const size_t mo = (size_t)row * 484;
    for (int j = lane; j < 484; j += 64) {
        const int part = div44(j), c = j - part*44;
        float v = 0.f;
        if (c < c_sizes[part]) {
            const int so = c_offs[part] + c;
            v = fmaxf(xss[so], x2s[so]);
        }
        m12[mo + j] = v;
    }
}

// ---------------- rnorm over bf16 p (stride 512, cols>=484 zero) ------------
__global__ __launch_bounds__(256)
void k_rnorm(const unsigned short* __restrict__ p, float* __restrict__ rnorm)
{
    const int row  = blockIdx.x * 4 + (threadIdx.x >> 6);
    const int lane = threadIdx.x & 63;
    const bfrag8 v8 = *(const bfrag8*)(p + (size_t)row * 512 + lane * 8);
    float ss = 0.f;
    #pragma unroll
    for (int t = 0; t < 8; ++t) { const float f = bf2f((unsigned short)v8[t]); ss += f*f; }
    #pragma unroll
    for (int o = 32; o; o >>= 1) ss += __shfl_xor(ss, o);
    if (lane == 0) rnorm[row] = 1.f / fmaxf(sqrtf(ss), 1e-12f);
}

// ---------------- bf16 MFMA GEMM: C = A(M,K) @ W(N,K)^T + epilogue ----------
// MODE 0: acc + bias[n]
// MODE 1: n<NLOG ? max(sigmoid(acc), m12[m*484+n]) : 0
// MODE 2: (n<272 ? rn[m]*acc : acc) + bias[n]   (extra=rnorm)
// MODE 3: relu(acc + bias[n])
// MODE 4: n<NLOG: C(bf16)[m*ldc+n]=acc+bias[n]; n in [1536,1587): C2[m*51+n-1536]
// Grid: m-major (round-8 measured layout).
template<int MODE, typename CT>
__global__ __launch_bounds__(256)
void k_gemm_mfma(const unsigned short* __restrict__ A, int lda,
                 const unsigned short* __restrict__ W, int ldw,
                 CT* __restrict__ C, int ldc,
                 const float* __restrict__ bias,
                 const float* __restrict__ extra,
                 const float* __restrict__ m12,
                 float* __restrict__ C2,
                 int K, int NSTORE, int NLOG)
{
    __shared__ unsigned short Asm[128*64];
    __shared__ unsigned short Bsm[128*64];
    const int tid  = threadIdx.x;
    const int wave = tid >> 6, lane = tid & 63;
    const int m0 = blockIdx.x * 128;
    const int n0 = blockIdx.y * 128;
    const int wr = (wave >> 1) << 6;
    const int wc = (wave & 1) << 6;

    f32x4 acc[4][4];
    #pragma unroll
    for (int i = 0; i < 4; ++i)
        #pragma unroll
        for (int j = 0; j < 4; ++j) acc[i][j] = (f32x4){0.f,0.f,0.f,0.f};

    const int ci_base = wave * 64 + lane;
    const int lrow = lane & 15;
    const int lk   = lane >> 4;

    const int nkt = K >> 6;
    for (int kt = 0; kt < nkt; ++kt) {
        const int k0 = kt << 6;
        #pragma unroll
        for (int c = 0; c < 4; ++c) {
            const int ci   = c * 256 + ci_base;
            const int row  = ci >> 3;
            const int slot = ci & 7;
            const int gc   = k0 + (((slot ^ (row & 7)) & 7) << 3);
            __builtin_amdgcn_global_load_lds(
                (const __attribute__((address_space(1))) void*)(A + (size_t)(m0 + row) * lda + gc),
                (__attribute__((address_space(3))) void*)(Asm + (c*4 + wave) * 512),
                16, 0, 0);
            __builtin_amdgcn_global_load_lds(
                (const __attribute__((address_space(1))) void*)(W + (size_t)(n0 + row) * ldw + gc),
                (__attribute__((address_space(3))) void*)(Bsm + (c*4 + wave) * 512),
                16, 0, 0);
        }
        __syncthreads();
        #pragma unroll
        for (int kk = 0; kk < 2; ++kk) {
            bfrag8 af[4], bfr[4];
            #pragma unroll
            for (int f = 0; f < 4; ++f) {
                const int r = wr + f*16 + lrow;
                const int s = kk*4 + lk;
                af[f]  = *(const bfrag8*)((const char*)Asm + r*128 + ((s ^ (r & 7)) << 4));
                const int n = wc + f*16 + lrow;
                bfr[f] = *(const bfrag8*)((const char*)Bsm + n*128 + ((s ^ (n & 7)) << 4));
            }
            #pragma unroll
            for (int i = 0; i < 4; ++i)
                #pragma unroll
                for (int j = 0; j < 4; ++j)
                    acc[i][j] = __builtin_amdgcn_mfma_f32_16x16x32_bf16(af[i], bfr[j], acc[i][j], 0, 0, 0);
        }
        __syncthreads();
    }

    const int lr4 = (lane >> 4) << 2;
    const int lc  = lane & 15;
    #pragma unroll
    for (int i = 0; i < 4; ++i) {
        #pragma unroll
        for (int r = 0; r < 4; ++r) {
            const int m = m0 + wr + i*16 + lr4 + r;
            CT* crow = C + (size_t)m * ldc;
            float ex = 0.f;
            if (MODE == 2) ex = extra[m];
            #pragma unroll
            for (int j = 0; j < 4; ++j) {
                const int n = n0 + wc + j*16 + lc;
                if (n >= NSTORE) continue;
                const float a = acc[i][j][r];
                if (MODE == 4) {
                    if (n < NLOG)
                        crow[n] = (CT)f2bf(a + bias[n]);
                    else if (n >= 1536 && n < 1587)
                        C2[(size_t)m*51 + (n - 1536)] = a + bias[n];
                    continue;
                }
                float v;
                if (MODE == 0)      v = a + bias[n];
                else if (MODE == 1) v = (n < NLOG) ? fmaxf(1.f/(1.f + expf(-a)), m12[(size_t)m*484 + n]) : 0.f;
                else if (MODE == 2) v = ((n < 272) ? ex * a : a) + bias[n];
                else                v = fmaxf(a + bias[n], 0.f);
                if constexpr (sizeof(CT) == 2) crow[n] = (CT)f2bf(v);
                else                           crow[n] = v;
            }
        }
    }
}

// ---------------- dueling combine + softmax(51) — round-8 structure ---------
// adv is bf16 in d_out at this row's base (3060B); block stages it to LDS,
// then overwrites the same 6120B region with f32 softmax. Race-free per row.
__global__ __launch_bounds__(256)
void k_soft(float* out, const float* __restrict__ vf)
{
    const int row = blockIdx.x;
    const int tid = threadIdx.x;
    __shared__ float s_adv[30*51];
    __shared__ float s_vfm[51];
    const unsigned int* arow = (const unsigned int*)(out + (size_t)row * 1530);
    for (int i = tid; i < 765; i += 256) {
        const unsigned int u = arow[i];
        s_adv[2*i]   = bf2f((unsigned short)(u & 0xffffu));
        s_adv[2*i+1] = bf2f((unsigned short)(u >> 16));
    }
    __syncthreads();
    if (tid < 51) {
        float s = 0.f;
        #pragma unroll
        for (int n = 0; n < 30; ++n) s += s_adv[n*51 + tid];
        s_vfm[tid] = vf[(size_t)row*51 + tid] - s * (1.f/30.f);
    }
    __syncthreads();
    const int w = tid >> 6, lane = tid & 63;
    float* orow = out + (size_t)row * 1530;
    for (int n = w; n < 30; n += 4) {
        const float v = (lane < 51) ? (s_adv[n*51 + lane] + s_vfm[lane]) : -INFINITY;
        float mx = v;
        #pragma unroll
        for (int o = 32; o; o >>= 1) mx = fmaxf(mx, __shfl_xor(mx, o));
        const float e = (lane < 51) ? expf(v - mx) : 0.f;
        float s = e;
        #pragma unroll
        for (int o = 32; o; o >>= 1) s += __shfl_xor(s, o);
        if (lane < 51) orow[n*51 + lane] = e / s;
    }
}

// ---------------------------------------------------------------------------
extern "C" void kernel_launch(void* const* d_in, const int* in_sizes, int n_in,
                              void* d_out, int out_size, void* d_ws, size_t ws_size,
                              hipStream_t stream)
{
    const float* in1  = (const float*)d_in[0];
    const float* in2  = (const float*)d_in[1];
    const float* ins  = (const float*)d_in[2];
    const float* W_g  = (const float*)d_in[3];
    const float* Wffl = (const float*)d_in[6];
    const float* bffl = (const float*)d_in[7];
    const float* Wp   = (const float*)d_in[12];
    const float* bp   = (const float*)d_in[13];
    const float* Wao  = (const float*)d_in[14];
    const float* bao  = (const float*)d_in[15];
    const float* Wa1  = (const float*)d_in[16];
    const float* ba1  = (const float*)d_in[17];
    const float* Wa2  = (const float*)d_in[18];
    const float* ba2  = (const float*)d_in[19];
    const float* Wv1  = (const float*)d_in[20];
    const float* bv1  = (const float*)d_in[21];
    const float* Wv2  = (const float*)d_in[22];
    const float* bv2  = (const float*)d_in[23];

    const int B = in_sizes[0] / 272;   // 32768

    // ws (bytes): [0,B*2048) h bf16 (early: att1@0, pooled@B*1024)
    //   [B*2048,B*3072) p bf16 ; [B*3072,+B*204) vf f32 ; rnorm ; weights
    char* ws = (char*)d_ws;
    unsigned short* att1   = (unsigned short*)ws;
    unsigned short* pooled = (unsigned short*)(ws + (size_t)B * 1024);
    unsigned short* hbuf   = (unsigned short*)ws;
    unsigned short* pbuf   = (unsigned short*)(ws + (size_t)B * 2048);
    float*          vf     = (float*)(ws + (size_t)B * 3072);
    float*          rnorm  = (float*)(ws + (size_t)B * 3072 + (size_t)B * 204);
    unsigned short* wgT    = (unsigned short*)((char*)rnorm + (size_t)B * 4);
    unsigned short* wpw    = wgT + 512*512;
    unsigned short* w4     = wpw + 512*512;
    unsigned short* w5     = w4  + 640*512;
    unsigned short* wcomb  = w5  + 1024*576;
    float*          biases = (float*)(wcomb + 1664*1024);

    // d_out: m12 f32 (B,484) @0 until K2; x bf16 (B,576) @float-offset B*512
    // until K5; adv bf16 (row stride 3060 ushorts = 6120B) until k_soft; f32.
    float*          m12  = (float*)d_out;
    unsigned short* xbuf = (unsigned short*)((float*)d_out + (size_t)B * 512);
    unsigned short* advb = (unsigned short*)d_out;
    float*          out  = (float*)d_out;

    const int gm = B / 128;

    k_conv<<<dim3(3072, 6), 256, 0, stream>>>(W_g, Wp, Wffl, Wao, Wa1, Wv1, Wa2, Wv2,
                                              bp, bffl, bao, ba1, bv1, ba2, bv2,
                                              wgT, wpw, w4, w5, wcomb, biases);
    k_prep<<<B, 64, 0, stream>>>(in1, in2, ins, att1, m12);
    // pooled = max(sigmoid(att1 @ W_g), m12)
    k_gemm_mfma<1, unsigned short><<<dim3(gm, 4), 256, 0, stream>>>(
        att1, 512, wgT, 512, pooled, 512, nullptr, nullptr, m12, nullptr, 512, 512, 484);
    // p = pooled @ Wp^T + bp
    k_gemm_mfma<0, unsigned short><<<dim3(gm, 4), 256, 0, stream>>>(
        pooled, 512, wpw, 512, pbuf, 512, biases + 0, nullptr, nullptr, nullptr, 512, 512, 512);
    k_rnorm<<<B / 4, 256, 0, stream>>>(pbuf, rnorm);
    // x = [rn*(p@Wffl^T)+bffl | p@Wao^T+bao]  (B,576)
    k_gemm_mfma<2, unsigned short><<<dim3(gm, 5), 256, 0, stream>>>(
        pbuf, 512, w4, 512, xbuf, 576, biases + 512, rnorm, nullptr, nullptr, 512, 576, 576);
    // h = relu(x @ w5^T + b5)  (B,1024)
    k_gemm_mfma<3, unsigned short><<<dim3(gm, 8), 256, 0, stream>>>(
        xbuf, 576, w5, 576, hbuf, 1024, biases + 1152, nullptr, nullptr, nullptr, 576, 1024, 1024);
    // [adv | vf] = h @ wcomb^T : adv bf16 -> d_out (stride 3060), vf f32 -> vf
    k_gemm_mfma<4, unsigned short><<<dim3(gm, 13), 256, 0, stream>>>(
        hbuf, 1024, wcomb, 1024, advb, 3060, biases + 2176, nullptr, nullptr, vf, 1024, 1664, 1530);
    // dueling combine + softmax
    k_soft<<<B, 256, 0, stream>>>(out, vf);
}